// Round 3
// baseline (323.605 us; speedup 1.0000x reference)
//
#include <hip/hip_runtime.h>
#include <math.h>

#define NSEG 126

__device__ __forceinline__ unsigned bitrev8(unsigned v) { return __brev(v) >> 24; }

// ---------------------------------------------------------------------------
// Register-resident 256-point DIF FFT across one wave (64 lanes x 4 float2).
// Element e = i*64 + lane. On exit x[i] holds X[bitrev8(e)].
// ---------------------------------------------------------------------------
__device__ __forceinline__ void fft256(float2 x[4], int lane) {
    const float PI = 3.14159265358979323846f;
    {
        float s, c;
        __sincosf(-PI * (float)lane * (1.0f / 128.0f), &s, &c);
        float2 w0 = make_float2(c, s);       // j = lane
        float2 w1 = make_float2(s, -c);      // j = lane+64 : w0 * (-i)
        float2 u, t, d;
        u = x[0]; t = x[2];
        x[0] = make_float2(u.x + t.x, u.y + t.y);
        d = make_float2(u.x - t.x, u.y - t.y);
        x[2] = make_float2(d.x * w0.x - d.y * w0.y, d.x * w0.y + d.y * w0.x);
        u = x[1]; t = x[3];
        x[1] = make_float2(u.x + t.x, u.y + t.y);
        d = make_float2(u.x - t.x, u.y - t.y);
        x[3] = make_float2(d.x * w1.x - d.y * w1.y, d.x * w1.y + d.y * w1.x);
    }
    {
        float s, c;
        __sincosf(-PI * (float)lane * (1.0f / 64.0f), &s, &c);
        float2 w = make_float2(c, s);
        float2 u, t, d;
        u = x[0]; t = x[1];
        x[0] = make_float2(u.x + t.x, u.y + t.y);
        d = make_float2(u.x - t.x, u.y - t.y);
        x[1] = make_float2(d.x * w.x - d.y * w.y, d.x * w.y + d.y * w.x);
        u = x[2]; t = x[3];
        x[2] = make_float2(u.x + t.x, u.y + t.y);
        d = make_float2(u.x - t.x, u.y - t.y);
        x[3] = make_float2(d.x * w.x - d.y * w.y, d.x * w.y + d.y * w.x);
    }
    #pragma unroll
    for (int hbit = 5; hbit >= 0; hbit--) {
        int h = 1 << hbit;
        int j = lane & (h - 1);
        float s, c;
        __sincosf(-PI * (float)j / (float)h, &s, &c);
        bool up = (lane & h) != 0;
        #pragma unroll
        for (int i = 0; i < 4; i++) {
            float px = __shfl_xor(x[i].x, h);
            float py = __shfl_xor(x[i].y, h);
            if (up) {
                float dx = px - x[i].x, dy = py - x[i].y;
                x[i] = make_float2(dx * c - dy * s, dx * s + dy * c);
            } else {
                x[i] = make_float2(x[i].x + px, x[i].y + py);
            }
        }
    }
}

// ---------------------------------------------------------------------------
// prep: keep half-plane (c>128, or c==128 && r>128); bucket j = 255-c in
// [1,127]; store packed (bitrev(r), bitrev(256-r), seg) per point.
// ---------------------------------------------------------------------------
__global__ void prep_zero(float* acc, int* counts) {
    int i = threadIdx.x;                          // 512 threads
    if (i < NSEG * 3) acc[i] = 0.f;
    if (i < 128) counts[i] = 0;
}

__device__ __forceinline__ bool keep_point(int r, int c) {
    return (c > 128) || (c == 128 && r > 128);
}

__global__ void prep_hist(const int* __restrict__ rr, const int* __restrict__ cc,
                          int n, int* counts) {
    int i = blockIdx.x * 256 + threadIdx.x;
    if (i < n) {
        int c = cc[i], r = rr[i];
        if (keep_point(r, c)) atomicAdd(&counts[255 - c], 1);
    }
}

__global__ void prep_scan(const int* __restrict__ counts, int* starts, int* cursor) {
    int lane = threadIdx.x;                      // 64 threads, 2 counts each
    int2 c = reinterpret_cast<const int2*>(counts)[lane];
    int lsum = c.x + c.y;
    int pre = lsum;
    #pragma unroll
    for (int off = 1; off < 64; off <<= 1) {
        int v = __shfl_up(pre, off);
        if (lane >= off) pre += v;
    }
    int excl = pre - lsum;
    int2 outv = make_int2(excl, excl + c.x);
    reinterpret_cast<int2*>(starts)[lane] = outv;
    reinterpret_cast<int2*>(cursor)[lane] = outv;
    if (lane == 63) starts[128] = excl + c.x + c.y;
}

__global__ void prep_scatter(const int* __restrict__ rr, const int* __restrict__ cc,
                             const int* __restrict__ seg, int n, int* cursor,
                             int* b_pack) {
    int i = blockIdx.x * 256 + threadIdx.x;
    if (i < n) {
        int c = cc[i], r = rr[i];
        if (keep_point(r, c)) {
            int j = 255 - c;
            int pos = atomicAdd(&cursor[j], 1);
            int pr = (int)bitrev8((unsigned)r);
            int pm = (int)bitrev8((unsigned)(256 - r) & 255);
            b_pack[pos] = pr | (pm << 8) | (seg[i] << 16);
        }
    }
}

// ---------------------------------------------------------------------------
// Row-pass: packed z = in + i*tgt, one row per wave, 16 rows/block.
// Output transposed: Gt physical row q (0..255) holds X[bitrev8(q)], x-major.
// ---------------------------------------------------------------------------
__global__ __launch_bounds__(1024) void rowfft_kernel(
    const float* __restrict__ inp, const float* __restrict__ tgt,
    float2* __restrict__ G, int pair_base)
{
    __shared__ float2 T[256 * 17];
    int bid    = blockIdx.x;
    int plocal = bid >> 4;
    int rowgrp = bid & 15;
    int wv     = threadIdx.x >> 6;
    int lane   = threadIdx.x & 63;
    int row    = (rowgrp << 4) + wv;
    size_t base = (((size_t)(pair_base + plocal)) << 16) + ((size_t)row << 8);
    const float* s1 = inp + base;
    const float* s2 = tgt + base;

    float2 x[4];
    #pragma unroll
    for (int i = 0; i < 4; i++) {
        int e = i * 64 + lane;
        x[i] = make_float2(s1[e], s2[e]);
    }
    fft256(x, lane);

    #pragma unroll
    for (int i = 0; i < 4; i++) T[(i * 64 + lane) * 17 + wv] = x[i];
    __syncthreads();

    float2* dst = G + (((size_t)plocal) << 16) + (rowgrp << 4);
    int xl = threadIdx.x & 15;
    int qb = threadIdx.x >> 4;                    // 0..63
    #pragma unroll
    for (int ii = 0; ii < 4; ii++) {
        int q = qb + (ii << 6);
        dst[q * 256 + xl] = T[q * 17 + xl];
    }
}

// ---------------------------------------------------------------------------
// Column-pass + gather. 512 threads = 8 waves = 4 column pairs {v, 256-v}.
// Wave loads its column contiguously from Gt, register FFT, F to LDS, gather.
// ---------------------------------------------------------------------------
__global__ __launch_bounds__(512) void colfft_gather_kernel(
    const float2* __restrict__ G, const int* __restrict__ starts,
    const int* __restrict__ b_pack, float* __restrict__ acc)
{
    __shared__ float2 Fb[8 * 256];
    __shared__ float accl[NSEG * 3];
    int tid    = threadIdx.x;
    int wv     = tid >> 6;
    int lane   = tid & 63;
    int plocal = blockIdx.x >> 5;
    int b      = blockIdx.x & 31;
    int kp     = wv & 3;
    int j      = (b << 2) + kp;                   // bucket 0..127
    int v      = (wv < 4) ? (j + 1) : (255 - j);  // low / high column
    int q      = (int)bitrev8((unsigned)v);

    for (int i = tid; i < NSEG * 3; i += 512) accl[i] = 0.f;

    const float2* col = G + (((size_t)plocal) << 16) + ((size_t)q << 8);
    float2 x[4];
    #pragma unroll
    for (int i = 0; i < 4; i++) x[i] = col[i * 64 + lane];

    fft256(x, lane);

    float2* F = Fb + (wv << 8);
    #pragma unroll
    for (int i = 0; i < 4; i++) F[i * 64 + lane] = x[i];
    __syncthreads();

    // gather bucket j; wave pair (kp, kp+4) splits the range
    const float2* F_lo = Fb + (kp << 8);          // column 256-c
    const float2* F_hi = Fb + ((4 + kp) << 8);    // column c
    int s0 = starts[j] + ((wv < 4) ? 0 : 64);
    int s1 = starts[j + 1];
    for (int e = s0 + lane; e < s1; e += 128) {
        int pk = b_pack[e];
        float2 a = F_hi[pk & 255];                // Fp(r, c)
        float2 m = F_lo[(pk >> 8) & 255];         // Fp(-r, -c)
        int sg = pk >> 16;
        float f1x = a.x + m.x, f1y = a.y - m.y;   // 2*F1
        float dx  = a.x - m.x, dy  = a.y + m.y;   // 2*i*F2 -> F2 = (dy, -dx)/2
        atomicAdd(&accl[sg * 3 + 0], f1x * dy - f1y * dx);   // 4*Re(F1*conj F2)
        atomicAdd(&accl[sg * 3 + 1], f1x * f1x + f1y * f1y); // 4*|F1|^2
        atomicAdd(&accl[sg * 3 + 2], dx * dx + dy * dy);     // 4*|F2|^2
    }
    __syncthreads();

    for (int i = tid; i < NSEG * 3; i += 512) {
        float s = accl[i];
        if (s != 0.f) atomicAdd(&acc[i], s);
    }
}

// ---------------------------------------------------------------------------
__global__ void final_kernel(const float* __restrict__ acc, const float* __restrict__ w,
                             float* __restrict__ out, float scale) {
    int lane = threadIdx.x;                       // 64 threads
    float val = 0.f;
    for (int s = lane; s < NSEG; s += 64) {
        float cr = acc[s * 3 + 0];
        float p1 = acc[s * 3 + 1];
        float p2 = acc[s * 3 + 2];
        float den = p1 * p2;
        float curve = den > 0.f ? fabsf(cr) * rsqrtf(den) : 0.f;
        val += curve * w[s + 1];
    }
    if (lane == 0) val += w[0];                   // curve[0] = 1
    #pragma unroll
    for (int off = 32; off > 0; off >>= 1) val += __shfl_down(val, off);
    if (lane == 0) out[0] = scale * val;
}

// ---------------------------------------------------------------------------
extern "C" void kernel_launch(void* const* d_in, const int* in_sizes, int n_in,
                              void* d_out, int out_size, void* d_ws, size_t ws_size,
                              hipStream_t stream)
{
    const float* inp = (const float*)d_in[0];
    const float* tgt = (const float*)d_in[1];
    const float* wts = (const float*)d_in[2];
    const int*   rr  = (const int*)d_in[3];
    const int*   cc  = (const int*)d_in[4];
    const int*   sg  = (const int*)d_in[5];
    int npts   = in_sizes[3];
    int npairs = in_sizes[0] >> 16;               // B*C (65536 px/img)

    char* ws = (char*)d_ws;
    float* acc    = (float*)(ws + 0);             // 378 floats
    int*   counts = (int*)(ws + 2048);            // 128 ints
    int*   starts = (int*)(ws + 2560);            // 129 ints
    int*   cursor = (int*)(ws + 3584);            // 128 ints
    int*   b_pack = (int*)(ws + 4096);
    size_t goff = 4096 + (size_t)npts * 4;
    goff = (goff + 255) & ~(size_t)255;
    float2* G = (float2*)(ws + goff);

    size_t per_pair = (size_t)256 * 256 * sizeof(float2);   // 512 KiB
    int maxchunk = (int)((ws_size > goff ? (ws_size - goff) : 0) / per_pair);
    if (maxchunk < 1) maxchunk = 1;
    if (maxchunk > npairs) maxchunk = npairs;

    prep_zero<<<1, 512, 0, stream>>>(acc, counts);
    prep_hist<<<(npts + 255) / 256, 256, 0, stream>>>(rr, cc, npts, counts);
    prep_scan<<<1, 64, 0, stream>>>(counts, starts, cursor);
    prep_scatter<<<(npts + 255) / 256, 256, 0, stream>>>(rr, cc, sg, npts, cursor, b_pack);

    for (int pb = 0; pb < npairs; pb += maxchunk) {
        int cp = npairs - pb < maxchunk ? npairs - pb : maxchunk;
        rowfft_kernel<<<cp * 16, 1024, 0, stream>>>(inp, tgt, G, pb);
        colfft_gather_kernel<<<cp * 32, 512, 0, stream>>>(G, starts, b_pack, acc);
    }

    final_kernel<<<1, 64, 0, stream>>>(acc, wts, (float*)d_out, (float)npairs);
}

// Round 4
// 270.799 us; speedup vs baseline: 1.1950x; 1.1950x over previous
//
#include <hip/hip_runtime.h>
#include <math.h>

#define NSEG 126

__device__ __forceinline__ unsigned bitrev8(unsigned v) { return __brev(v) >> 24; }

// ---------------------------------------------------------------------------
// K interleaved register-resident 256-point DIF FFTs per wave.
// FFT k: element e = i*64 + lane lives in x[k][i]. On exit x[k][i] = X[bitrev8(e)].
// Twiddles depend only on (lane, stage) -> computed once, shared across k.
// ---------------------------------------------------------------------------
template <int K>
__device__ __forceinline__ void fftK(float2 x[][4], int lane) {
    const float PI = 3.14159265358979323846f;
    {   // stage M=256: pairs (0,2),(1,3); twiddle j=lane and j=lane+64
        float s, c;
        __sincosf(-PI * (float)lane * (1.0f / 128.0f), &s, &c);
        #pragma unroll
        for (int k = 0; k < K; k++) {
            float2 u, t, d;
            u = x[k][0]; t = x[k][2];
            x[k][0] = make_float2(u.x + t.x, u.y + t.y);
            d = make_float2(u.x - t.x, u.y - t.y);
            x[k][2] = make_float2(d.x * c - d.y * s, d.x * s + d.y * c);
            u = x[k][1]; t = x[k][3];
            x[k][1] = make_float2(u.x + t.x, u.y + t.y);
            d = make_float2(u.x - t.x, u.y - t.y);
            x[k][3] = make_float2(d.x * s + d.y * c, -d.x * c + d.y * s); // * (s,-c)
        }
    }
    {   // stage M=128: pairs (0,1),(2,3); twiddle j=lane for both
        float s, c;
        __sincosf(-PI * (float)lane * (1.0f / 64.0f), &s, &c);
        #pragma unroll
        for (int k = 0; k < K; k++) {
            float2 u, t, d;
            u = x[k][0]; t = x[k][1];
            x[k][0] = make_float2(u.x + t.x, u.y + t.y);
            d = make_float2(u.x - t.x, u.y - t.y);
            x[k][1] = make_float2(d.x * c - d.y * s, d.x * s + d.y * c);
            u = x[k][2]; t = x[k][3];
            x[k][2] = make_float2(u.x + t.x, u.y + t.y);
            d = make_float2(u.x - t.x, u.y - t.y);
            x[k][3] = make_float2(d.x * c - d.y * s, d.x * s + d.y * c);
        }
    }
    #pragma unroll
    for (int hbit = 5; hbit >= 0; hbit--) {   // stages M=64..2, cross-lane
        int h = 1 << hbit;
        int j = lane & (h - 1);
        float s, c;
        __sincosf(-PI * (float)j / (float)h, &s, &c);
        bool up = (lane & h) != 0;
        #pragma unroll
        for (int k = 0; k < K; k++) {
            #pragma unroll
            for (int i = 0; i < 4; i++) {
                float px = __shfl_xor(x[k][i].x, h);
                float py = __shfl_xor(x[k][i].y, h);
                if (up) {
                    float dx = px - x[k][i].x, dy = py - x[k][i].y;
                    x[k][i] = make_float2(dx * c - dy * s, dx * s + dy * c);
                } else {
                    x[k][i] = make_float2(x[k][i].x + px, x[k][i].y + py);
                }
            }
        }
    }
}

// ---------------------------------------------------------------------------
// prep: keep half-plane (c>128 || (c==128 && r>128)); bucket j = 255-c;
// pack (bitrev(r), bitrev(256-r), seg).
// ---------------------------------------------------------------------------
__global__ void prep_zero(float* acc, int* counts) {
    int i = threadIdx.x;                          // 512 threads
    if (i < NSEG * 3) acc[i] = 0.f;
    if (i < 128) counts[i] = 0;
}

__device__ __forceinline__ bool keep_point(int r, int c) {
    return (c > 128) || (c == 128 && r > 128);
}

__global__ void prep_hist(const int* __restrict__ rr, const int* __restrict__ cc,
                          int n, int* counts) {
    int i = blockIdx.x * 256 + threadIdx.x;
    if (i < n) {
        int c = cc[i], r = rr[i];
        if (keep_point(r, c)) atomicAdd(&counts[255 - c], 1);
    }
}

__global__ void prep_scan(const int* __restrict__ counts, int* starts, int* cursor) {
    int lane = threadIdx.x;                      // 64 threads, 2 counts each
    int2 c = reinterpret_cast<const int2*>(counts)[lane];
    int lsum = c.x + c.y;
    int pre = lsum;
    #pragma unroll
    for (int off = 1; off < 64; off <<= 1) {
        int v = __shfl_up(pre, off);
        if (lane >= off) pre += v;
    }
    int excl = pre - lsum;
    int2 outv = make_int2(excl, excl + c.x);
    reinterpret_cast<int2*>(starts)[lane] = outv;
    reinterpret_cast<int2*>(cursor)[lane] = outv;
    if (lane == 63) starts[128] = excl + c.x + c.y;
}

__global__ void prep_scatter(const int* __restrict__ rr, const int* __restrict__ cc,
                             const int* __restrict__ seg, int n, int* cursor,
                             int* b_pack) {
    int i = blockIdx.x * 256 + threadIdx.x;
    if (i < n) {
        int c = cc[i], r = rr[i];
        if (keep_point(r, c)) {
            int j = 255 - c;
            int pos = atomicAdd(&cursor[j], 1);
            int pr = (int)bitrev8((unsigned)r);
            int pm = (int)bitrev8((unsigned)(256 - r) & 255);
            b_pack[pos] = pr | (pm << 8) | (seg[i] << 16);
        }
    }
}

// ---------------------------------------------------------------------------
// Row-pass: packed z = in + i*tgt; 2 rows per wave, 8 waves -> 16 rows/block.
// Output transposed: Gt physical row q holds X[bitrev8(q)], x-major.
// ---------------------------------------------------------------------------
__global__ __launch_bounds__(512) void rowfft_kernel(
    const float* __restrict__ inp, const float* __restrict__ tgt,
    float2* __restrict__ G, int pair_base)
{
    __shared__ float2 T[256 * 17];
    int bid    = blockIdx.x;
    int plocal = bid >> 4;
    int rowgrp = bid & 15;
    int wv     = threadIdx.x >> 6;
    int lane   = threadIdx.x & 63;
    size_t base = (((size_t)(pair_base + plocal)) << 16)
                + ((size_t)((rowgrp << 4) + (wv << 1)) << 8);
    const float* s1 = inp + base;
    const float* s2 = tgt + base;

    float2 x[2][4];
    #pragma unroll
    for (int k = 0; k < 2; k++)
        #pragma unroll
        for (int i = 0; i < 4; i++) {
            int e = (k << 8) + i * 64 + lane;
            x[k][i] = make_float2(s1[e], s2[e]);
        }
    fftK<2>(x, lane);

    #pragma unroll
    for (int k = 0; k < 2; k++)
        #pragma unroll
        for (int i = 0; i < 4; i++)
            T[(i * 64 + lane) * 17 + (wv << 1) + k] = x[k][i];
    __syncthreads();

    float2* dst = G + (((size_t)plocal) << 16) + (rowgrp << 4);
    int xl = threadIdx.x & 15;
    int qb = threadIdx.x >> 4;                    // 0..31
    #pragma unroll
    for (int ii = 0; ii < 8; ii++) {
        int q = qb + (ii << 5);
        dst[q * 256 + xl] = T[q * 17 + xl];
    }
}

// ---------------------------------------------------------------------------
// Column-pass + gather. 256 threads = 4 waves; each wave owns 2 buckets and
// computes their 4 columns {j+1, 255-j, j+2, 254-j} itself -> gather is
// wave-local (no inter-wave barrier between FFT and gather).
// ---------------------------------------------------------------------------
__global__ __launch_bounds__(256) void colfft_gather_kernel(
    const float2* __restrict__ G, const int* __restrict__ starts,
    const int* __restrict__ b_pack, float* __restrict__ acc)
{
    __shared__ float2 Fb[4][4][256];             // 32 KiB
    __shared__ float accl[NSEG * 3];
    int tid    = threadIdx.x;
    int wv     = tid >> 6;
    int lane   = tid & 63;
    int plocal = blockIdx.x >> 4;
    int b      = blockIdx.x & 15;
    int jbase  = (b << 3) + (wv << 1);           // this wave's buckets: jbase, jbase+1

    for (int i = tid; i < NSEG * 3; i += 256) accl[i] = 0.f;
    __syncthreads();

    const float2* Gp = G + (((size_t)plocal) << 16);
    int cols[4];
    cols[0] = jbase + 1;   cols[1] = 255 - jbase;        // bucket jbase   (lo, hi)
    cols[2] = jbase + 2;   cols[3] = 254 - jbase;        // bucket jbase+1 (lo, hi)

    float2 x[4][4];
    #pragma unroll
    for (int k = 0; k < 4; k++) {
        int q = (int)bitrev8((unsigned)cols[k]);
        const float2* col = Gp + ((size_t)q << 8);
        #pragma unroll
        for (int i = 0; i < 4; i++) x[k][i] = col[i * 64 + lane];
    }

    fftK<4>(x, lane);

    #pragma unroll
    for (int k = 0; k < 4; k++)
        #pragma unroll
        for (int i = 0; i < 4; i++)
            Fb[wv][k][i * 64 + lane] = x[k][i];
    // no __syncthreads: Fb slice + gather are same-wave (compiler waits lgkmcnt)

    #pragma unroll
    for (int kb = 0; kb < 2; kb++) {
        int j = jbase + kb;
        const float2* F_lo = Fb[wv][kb * 2 + 0];
        const float2* F_hi = Fb[wv][kb * 2 + 1];
        int s0 = starts[j], s1 = starts[j + 1];
        for (int e = s0 + lane; e < s1; e += 64) {
            int pk = b_pack[e];
            float2 a = F_hi[pk & 255];            // Fp(r, c)
            float2 m = F_lo[(pk >> 8) & 255];     // Fp(-r, -c)
            int sg = pk >> 16;
            float f1x = a.x + m.x, f1y = a.y - m.y;   // 2*F1
            float dx  = a.x - m.x, dy  = a.y + m.y;   // 2i*F2
            atomicAdd(&accl[sg * 3 + 0], f1x * dy - f1y * dx);
            atomicAdd(&accl[sg * 3 + 1], f1x * f1x + f1y * f1y);
            atomicAdd(&accl[sg * 3 + 2], dx * dx + dy * dy);
        }
    }
    __syncthreads();

    for (int i = tid; i < NSEG * 3; i += 256) {
        float v = accl[i];
        if (v != 0.f) atomicAdd(&acc[i], v);
    }
}

// ---------------------------------------------------------------------------
__global__ void final_kernel(const float* __restrict__ acc, const float* __restrict__ w,
                             float* __restrict__ out, float scale) {
    int lane = threadIdx.x;                       // 64 threads
    float val = 0.f;
    for (int s = lane; s < NSEG; s += 64) {
        float cr = acc[s * 3 + 0];
        float p1 = acc[s * 3 + 1];
        float p2 = acc[s * 3 + 2];
        float den = p1 * p2;
        float curve = den > 0.f ? fabsf(cr) * rsqrtf(den) : 0.f;
        val += curve * w[s + 1];
    }
    if (lane == 0) val += w[0];                   // curve[0] = 1
    #pragma unroll
    for (int off = 32; off > 0; off >>= 1) val += __shfl_down(val, off);
    if (lane == 0) out[0] = scale * val;
}

// ---------------------------------------------------------------------------
extern "C" void kernel_launch(void* const* d_in, const int* in_sizes, int n_in,
                              void* d_out, int out_size, void* d_ws, size_t ws_size,
                              hipStream_t stream)
{
    const float* inp = (const float*)d_in[0];
    const float* tgt = (const float*)d_in[1];
    const float* wts = (const float*)d_in[2];
    const int*   rr  = (const int*)d_in[3];
    const int*   cc  = (const int*)d_in[4];
    const int*   sg  = (const int*)d_in[5];
    int npts   = in_sizes[3];
    int npairs = in_sizes[0] >> 16;               // B*C (65536 px/img)

    char* ws = (char*)d_ws;
    float* acc    = (float*)(ws + 0);             // 378 floats
    int*   counts = (int*)(ws + 2048);            // 128 ints
    int*   starts = (int*)(ws + 2560);            // 129 ints
    int*   cursor = (int*)(ws + 3584);            // 128 ints
    int*   b_pack = (int*)(ws + 4096);
    size_t goff = 4096 + (size_t)npts * 4;
    goff = (goff + 255) & ~(size_t)255;
    float2* G = (float2*)(ws + goff);

    size_t per_pair = (size_t)256 * 256 * sizeof(float2);   // 512 KiB
    int maxchunk = (int)((ws_size > goff ? (ws_size - goff) : 0) / per_pair);
    if (maxchunk < 1) maxchunk = 1;
    if (maxchunk > npairs) maxchunk = npairs;

    prep_zero<<<1, 512, 0, stream>>>(acc, counts);
    prep_hist<<<(npts + 255) / 256, 256, 0, stream>>>(rr, cc, npts, counts);
    prep_scan<<<1, 64, 0, stream>>>(counts, starts, cursor);
    prep_scatter<<<(npts + 255) / 256, 256, 0, stream>>>(rr, cc, sg, npts, cursor, b_pack);

    for (int pb = 0; pb < npairs; pb += maxchunk) {
        int cp = npairs - pb < maxchunk ? npairs - pb : maxchunk;
        rowfft_kernel<<<cp * 16, 512, 0, stream>>>(inp, tgt, G, pb);
        colfft_gather_kernel<<<cp * 16, 256, 0, stream>>>(G, starts, b_pack, acc);
    }

    final_kernel<<<1, 64, 0, stream>>>(acc, wts, (float*)d_out, (float)npairs);
}

// Round 5
// 267.450 us; speedup vs baseline: 1.2100x; 1.0125x over previous
//
#include <hip/hip_runtime.h>
#include <math.h>

#define NSEG 126

__device__ __forceinline__ unsigned bitrev8(unsigned v) { return __brev(v) >> 24; }

// ---------------------------------------------------------------------------
// K interleaved register-resident 256-point DIF FFTs per wave.
// FFT k: element e = i*64 + lane lives in x[k][i]. On exit x[k][i] = X[bitrev8(e)].
// Twiddles depend only on (lane, stage) -> computed once, shared across k.
// ---------------------------------------------------------------------------
template <int K>
__device__ __forceinline__ void fftK(float2 x[][4], int lane) {
    const float PI = 3.14159265358979323846f;
    {   // stage M=256: pairs (0,2),(1,3); twiddle j=lane and j=lane+64
        float s, c;
        __sincosf(-PI * (float)lane * (1.0f / 128.0f), &s, &c);
        #pragma unroll
        for (int k = 0; k < K; k++) {
            float2 u, t, d;
            u = x[k][0]; t = x[k][2];
            x[k][0] = make_float2(u.x + t.x, u.y + t.y);
            d = make_float2(u.x - t.x, u.y - t.y);
            x[k][2] = make_float2(d.x * c - d.y * s, d.x * s + d.y * c);
            u = x[k][1]; t = x[k][3];
            x[k][1] = make_float2(u.x + t.x, u.y + t.y);
            d = make_float2(u.x - t.x, u.y - t.y);
            x[k][3] = make_float2(d.x * s + d.y * c, -d.x * c + d.y * s); // * (s,-c)
        }
    }
    {   // stage M=128: pairs (0,1),(2,3); twiddle j=lane for both
        float s, c;
        __sincosf(-PI * (float)lane * (1.0f / 64.0f), &s, &c);
        #pragma unroll
        for (int k = 0; k < K; k++) {
            float2 u, t, d;
            u = x[k][0]; t = x[k][1];
            x[k][0] = make_float2(u.x + t.x, u.y + t.y);
            d = make_float2(u.x - t.x, u.y - t.y);
            x[k][1] = make_float2(d.x * c - d.y * s, d.x * s + d.y * c);
            u = x[k][2]; t = x[k][3];
            x[k][2] = make_float2(u.x + t.x, u.y + t.y);
            d = make_float2(u.x - t.x, u.y - t.y);
            x[k][3] = make_float2(d.x * c - d.y * s, d.x * s + d.y * c);
        }
    }
    #pragma unroll
    for (int hbit = 5; hbit >= 0; hbit--) {   // stages M=64..2, cross-lane
        int h = 1 << hbit;
        int j = lane & (h - 1);
        float s, c;
        __sincosf(-PI * (float)j / (float)h, &s, &c);
        bool up = (lane & h) != 0;
        #pragma unroll
        for (int k = 0; k < K; k++) {
            #pragma unroll
            for (int i = 0; i < 4; i++) {
                float px = __shfl_xor(x[k][i].x, h);
                float py = __shfl_xor(x[k][i].y, h);
                if (up) {
                    float dx = px - x[k][i].x, dy = py - x[k][i].y;
                    x[k][i] = make_float2(dx * c - dy * s, dx * s + dy * c);
                } else {
                    x[k][i] = make_float2(x[k][i].x + px, x[k][i].y + py);
                }
            }
        }
    }
}

// ---------------------------------------------------------------------------
// prep: keep half-plane (c>128 || (c==128 && r>128)); bucket j = 255-c;
// pack (bitrev(r), bitrev(256-r), seg).
// ---------------------------------------------------------------------------
__global__ void prep_zero(float* acc, int* counts) {
    int i = threadIdx.x;                          // 512 threads
    if (i < NSEG * 3) acc[i] = 0.f;
    if (i < 128) counts[i] = 0;
}

__device__ __forceinline__ bool keep_point(int r, int c) {
    return (c > 128) || (c == 128 && r > 128);
}

__global__ void prep_hist(const int* __restrict__ rr, const int* __restrict__ cc,
                          int n, int* counts) {
    int i = blockIdx.x * 256 + threadIdx.x;
    if (i < n) {
        int c = cc[i], r = rr[i];
        if (keep_point(r, c)) atomicAdd(&counts[255 - c], 1);
    }
}

__global__ void prep_scan(const int* __restrict__ counts, int* starts, int* cursor) {
    int lane = threadIdx.x;                      // 64 threads, 2 counts each
    int2 c = reinterpret_cast<const int2*>(counts)[lane];
    int lsum = c.x + c.y;
    int pre = lsum;
    #pragma unroll
    for (int off = 1; off < 64; off <<= 1) {
        int v = __shfl_up(pre, off);
        if (lane >= off) pre += v;
    }
    int excl = pre - lsum;
    int2 outv = make_int2(excl, excl + c.x);
    reinterpret_cast<int2*>(starts)[lane] = outv;
    reinterpret_cast<int2*>(cursor)[lane] = outv;
    if (lane == 63) starts[128] = excl + c.x + c.y;
}

__global__ void prep_scatter(const int* __restrict__ rr, const int* __restrict__ cc,
                             const int* __restrict__ seg, int n, int* cursor,
                             int* b_pack) {
    int i = blockIdx.x * 256 + threadIdx.x;
    if (i < n) {
        int c = cc[i], r = rr[i];
        if (keep_point(r, c)) {
            int j = 255 - c;
            int pos = atomicAdd(&cursor[j], 1);
            int pr = (int)bitrev8((unsigned)r);
            int pm = (int)bitrev8((unsigned)(256 - r) & 255);
            b_pack[pos] = pr | (pm << 8) | (seg[i] << 16);
        }
    }
}

// ---------------------------------------------------------------------------
// Row-pass: packed z = in + i*tgt; 2 rows per wave, 8 waves -> 16 rows/block.
// Output transposed: Gt physical row q holds X[bitrev8(q)], x-major.
// ---------------------------------------------------------------------------
__global__ __launch_bounds__(512) void rowfft_kernel(
    const float* __restrict__ inp, const float* __restrict__ tgt,
    float2* __restrict__ G, int pair_base)
{
    __shared__ float2 T[256 * 17];
    int bid    = blockIdx.x;
    int plocal = bid >> 4;
    int rowgrp = bid & 15;
    int wv     = threadIdx.x >> 6;
    int lane   = threadIdx.x & 63;
    size_t base = (((size_t)(pair_base + plocal)) << 16)
                + ((size_t)((rowgrp << 4) + (wv << 1)) << 8);
    const float* s1 = inp + base;
    const float* s2 = tgt + base;

    float2 x[2][4];
    #pragma unroll
    for (int k = 0; k < 2; k++)
        #pragma unroll
        for (int i = 0; i < 4; i++) {
            int e = (k << 8) + i * 64 + lane;
            x[k][i] = make_float2(s1[e], s2[e]);
        }
    fftK<2>(x, lane);

    #pragma unroll
    for (int k = 0; k < 2; k++)
        #pragma unroll
        for (int i = 0; i < 4; i++)
            T[(i * 64 + lane) * 17 + (wv << 1) + k] = x[k][i];
    __syncthreads();

    float2* dst = G + (((size_t)plocal) << 16) + (rowgrp << 4);
    int xl = threadIdx.x & 15;
    int qb = threadIdx.x >> 4;                    // 0..31
    #pragma unroll
    for (int ii = 0; ii < 8; ii++) {
        int q = qb + (ii << 5);
        dst[q * 256 + xl] = T[q * 17 + xl];
    }
}

// ---------------------------------------------------------------------------
// Column-pass + gather. 256 threads = 4 waves; each wave owns 2 buckets
// (4 columns). Two-phase: store bucket-k's 2 columns in a 4 KiB per-wave LDS
// slot, gather, then reuse the slot for the next bucket (same-wave WAR only).
// LDS ~17.9 KiB -> 8 blocks/CU.
// ---------------------------------------------------------------------------
__global__ __launch_bounds__(256) void colfft_gather_kernel(
    const float2* __restrict__ G, const int* __restrict__ starts,
    const int* __restrict__ b_pack, float* __restrict__ acc)
{
    __shared__ float2 Fb[4][2][256];             // 16 KiB (per-wave bucket slot)
    __shared__ float accl[NSEG * 3];
    int tid    = threadIdx.x;
    int wv     = tid >> 6;
    int lane   = tid & 63;
    int plocal = blockIdx.x >> 4;
    int b      = blockIdx.x & 15;
    int jbase  = (b << 3) + (wv << 1);           // this wave's buckets: jbase, jbase+1

    for (int i = tid; i < NSEG * 3; i += 256) accl[i] = 0.f;
    __syncthreads();

    const float2* Gp = G + (((size_t)plocal) << 16);
    int cols[4];
    cols[0] = jbase + 1;   cols[1] = 255 - jbase;        // bucket jbase   (lo, hi)
    cols[2] = jbase + 2;   cols[3] = 254 - jbase;        // bucket jbase+1 (lo, hi)

    float2 x[4][4];
    #pragma unroll
    for (int k = 0; k < 4; k++) {
        int q = (int)bitrev8((unsigned)cols[k]);
        const float2* col = Gp + ((size_t)q << 8);
        #pragma unroll
        for (int i = 0; i < 4; i++) x[k][i] = col[i * 64 + lane];
    }

    fftK<4>(x, lane);

    float2* F_lo = &Fb[wv][0][0];
    float2* F_hi = &Fb[wv][1][0];
    #pragma unroll
    for (int kb = 0; kb < 2; kb++) {
        #pragma unroll
        for (int i = 0; i < 4; i++) {
            F_lo[i * 64 + lane] = x[2 * kb + 0][i];
            F_hi[i * 64 + lane] = x[2 * kb + 1][i];
        }
        int j = jbase + kb;
        int s0 = starts[j], s1 = starts[j + 1];
        int e  = s0 + lane;
        int pk = (e < s1) ? b_pack[e] : 0;       // pipelined global load
        while (e < s1) {
            int e2  = e + 64;
            int pk2 = (e2 < s1) ? b_pack[e2] : 0;
            float2 a = F_hi[pk & 255];            // Fp(r, c)
            float2 m = F_lo[(pk >> 8) & 255];     // Fp(-r, -c)
            int sg = pk >> 16;
            float f1x = a.x + m.x, f1y = a.y - m.y;   // 2*F1
            float dx  = a.x - m.x, dy  = a.y + m.y;   // 2i*F2
            atomicAdd(&accl[sg * 3 + 0], f1x * dy - f1y * dx);
            atomicAdd(&accl[sg * 3 + 1], f1x * f1x + f1y * f1y);
            atomicAdd(&accl[sg * 3 + 2], dx * dx + dy * dy);
            e = e2; pk = pk2;
        }
    }
    __syncthreads();

    for (int i = tid; i < NSEG * 3; i += 256) {
        float v = accl[i];
        if (v != 0.f) atomicAdd(&acc[i], v);
    }
}

// ---------------------------------------------------------------------------
__global__ void final_kernel(const float* __restrict__ acc, const float* __restrict__ w,
                             float* __restrict__ out, float scale) {
    int lane = threadIdx.x;                       // 64 threads
    float val = 0.f;
    for (int s = lane; s < NSEG; s += 64) {
        float cr = acc[s * 3 + 0];
        float p1 = acc[s * 3 + 1];
        float p2 = acc[s * 3 + 2];
        float den = p1 * p2;
        float curve = den > 0.f ? fabsf(cr) * rsqrtf(den) : 0.f;
        val += curve * w[s + 1];
    }
    if (lane == 0) val += w[0];                   // curve[0] = 1
    #pragma unroll
    for (int off = 32; off > 0; off >>= 1) val += __shfl_down(val, off);
    if (lane == 0) out[0] = scale * val;
}

// ---------------------------------------------------------------------------
extern "C" void kernel_launch(void* const* d_in, const int* in_sizes, int n_in,
                              void* d_out, int out_size, void* d_ws, size_t ws_size,
                              hipStream_t stream)
{
    const float* inp = (const float*)d_in[0];
    const float* tgt = (const float*)d_in[1];
    const float* wts = (const float*)d_in[2];
    const int*   rr  = (const int*)d_in[3];
    const int*   cc  = (const int*)d_in[4];
    const int*   sg  = (const int*)d_in[5];
    int npts   = in_sizes[3];
    int npairs = in_sizes[0] >> 16;               // B*C (65536 px/img)

    char* ws = (char*)d_ws;
    float* acc    = (float*)(ws + 0);             // 378 floats
    int*   counts = (int*)(ws + 2048);            // 128 ints
    int*   starts = (int*)(ws + 2560);            // 129 ints
    int*   cursor = (int*)(ws + 3584);            // 128 ints
    int*   b_pack = (int*)(ws + 4096);
    size_t goff = 4096 + (size_t)npts * 4;
    goff = (goff + 255) & ~(size_t)255;
    float2* G = (float2*)(ws + goff);

    size_t per_pair = (size_t)256 * 256 * sizeof(float2);   // 512 KiB
    int maxchunk = (int)((ws_size > goff ? (ws_size - goff) : 0) / per_pair);
    if (maxchunk < 1) maxchunk = 1;
    if (maxchunk > npairs) maxchunk = npairs;

    prep_zero<<<1, 512, 0, stream>>>(acc, counts);
    prep_hist<<<(npts + 255) / 256, 256, 0, stream>>>(rr, cc, npts, counts);
    prep_scan<<<1, 64, 0, stream>>>(counts, starts, cursor);
    prep_scatter<<<(npts + 255) / 256, 256, 0, stream>>>(rr, cc, sg, npts, cursor, b_pack);

    for (int pb = 0; pb < npairs; pb += maxchunk) {
        int cp = npairs - pb < maxchunk ? npairs - pb : maxchunk;
        rowfft_kernel<<<cp * 16, 512, 0, stream>>>(inp, tgt, G, pb);
        colfft_gather_kernel<<<cp * 16, 256, 0, stream>>>(G, starts, b_pack, acc);
    }

    final_kernel<<<1, 64, 0, stream>>>(acc, wts, (float*)d_out, (float)npairs);
}